// Round 4
// baseline (417.962 us; speedup 1.0000x reference)
//
#include <hip/hip_runtime.h>
#include <hip/hip_bf16.h>

#define BB 8
#define NN 2048
#define CC 256
#define DKK 64
#define DVV 256
#define COFF 60.0f

typedef __attribute__((ext_vector_type(8))) short bf16x8;
typedef __attribute__((ext_vector_type(4))) float f32x4;

#define MFMA16 __builtin_amdgcn_mfma_f32_16x16x32_bf16

static __device__ __forceinline__ unsigned short f2bf(float f) {
    unsigned int u = __float_as_uint(f);
    u += 0x7fffu + ((u >> 16) & 1u);
    return (unsigned short)(u >> 16);
}
static __device__ __forceinline__ float bf2f(unsigned short h) {
    return __uint_as_float(((unsigned int)h) << 16);
}

// ---------------- kernel 0: split W into bf16 h/l, rows: q(0..63)|k|v -----
__global__ void k_wt(const float* __restrict__ Wq, const float* __restrict__ Wk,
                     const float* __restrict__ Wv,
                     unsigned short* __restrict__ Wh, unsigned short* __restrict__ Wl) {
    int idx = blockIdx.x * 256 + threadIdx.x;
    if (idx >= 384 * 256) return;
    int d = idx >> 8, c = idx & 255;
    float w;
    if (d < 64)       w = Wq[d * 256 + c];
    else if (d < 128) w = Wk[(d - 64) * 256 + c];
    else              w = Wv[(d - 128) * 256 + c];
    unsigned short h = f2bf(w);
    Wh[idx] = h;
    Wl[idx] = f2bf(w - bf2f(h));
}

// ---------------- kernel 0b: split x into bf16 h/l ------------------------
__global__ __launch_bounds__(256) void k_split(
    const float* __restrict__ x,
    unsigned short* __restrict__ xh, unsigned short* __restrict__ xl) {
    int tid = blockIdx.x * 256 + threadIdx.x;
    const float4* xp = (const float4*)x + tid * 2;
    float4 a = xp[0], b = xp[1];
    float v[8] = {a.x, a.y, a.z, a.w, b.x, b.y, b.z, b.w};
    ushort4 h4[2], l4[2];
    #pragma unroll
    for (int i = 0; i < 8; ++i) {
        unsigned short h = f2bf(v[i]);
        ((unsigned short*)h4)[i] = h;
        ((unsigned short*)l4)[i] = f2bf(v[i] - bf2f(h));
    }
    ((ushort4*)xh)[tid * 2]     = h4[0];
    ((ushort4*)xh)[tid * 2 + 1] = h4[1];
    ((ushort4*)xl)[tid * 2]     = l4[0];
    ((ushort4*)xl)[tid * 2 + 1] = l4[1];
}

// ---------------- kernel 1a: v projection (single-pass bf16 MFMA) ---------
__global__ __launch_bounds__(256) void k_vproj(
    const unsigned short* __restrict__ xh, const unsigned short* __restrict__ Wh,
    unsigned short* __restrict__ vT)
{
    int w = threadIdx.x >> 6, lane = threadIdx.x & 63;
    int t = lane & 15, qd = lane >> 4;
    int n0 = blockIdx.x * 16;
    int bn = n0 + t;
    bf16x8 bfr[8];
    const unsigned short* bp = xh + (size_t)bn * 256 + qd * 8;
    #pragma unroll
    for (int c = 0; c < 8; ++c) bfr[c] = *(const bf16x8*)(bp + c * 32);
    #pragma unroll
    for (int k = 0; k < 4; ++k) {
        int dt = 8 + w * 4 + k;
        const unsigned short* ap = Wh + (size_t)(dt * 16 + t) * 256 + qd * 8;
        f32x4 acc = {0.f, 0.f, 0.f, 0.f};
        #pragma unroll
        for (int c = 0; c < 8; ++c) {
            bf16x8 a = *(const bf16x8*)(ap + c * 32);
            acc = MFMA16(a, bfr[c], acc, 0, 0, 0);
        }
        int b = bn >> 11, n = bn & 2047;
        #pragma unroll
        for (int r = 0; r < 4; ++r) {
            int dvd = dt * 16 + qd * 4 + r - 128;
            vT[((size_t)b * 256 + dvd) * 2048 + n] = f2bf(acc[r]);
        }
    }
}

// ---------------- kernel 1b: q/k projection (3-pass split-bf16 MFMA) ------
__global__ __launch_bounds__(256) void k_qkproj(
    const unsigned short* __restrict__ xh, const unsigned short* __restrict__ xl,
    const unsigned short* __restrict__ Wh, const unsigned short* __restrict__ Wl,
    unsigned short* __restrict__ qh, unsigned short* __restrict__ ql,
    unsigned short* __restrict__ kh, unsigned short* __restrict__ kl)
{
    int w = threadIdx.x >> 6, lane = threadIdx.x & 63;
    int t = lane & 15, qd = lane >> 4;
    int n0 = blockIdx.x * 16;
    int bn = n0 + t;
    bf16x8 bh[8], bl[8];
    const unsigned short* bph = xh + (size_t)bn * 256 + qd * 8;
    const unsigned short* bpl = xl + (size_t)bn * 256 + qd * 8;
    #pragma unroll
    for (int c = 0; c < 8; ++c) {
        bh[c] = *(const bf16x8*)(bph + c * 32);
        bl[c] = *(const bf16x8*)(bpl + c * 32);
    }
    #pragma unroll
    for (int k = 0; k < 2; ++k) {
        int dt = w * 2 + k;
        const unsigned short* aph = Wh + (size_t)(dt * 16 + t) * 256 + qd * 8;
        const unsigned short* apl = Wl + (size_t)(dt * 16 + t) * 256 + qd * 8;
        f32x4 acc = {0.f, 0.f, 0.f, 0.f};
        #pragma unroll
        for (int c = 0; c < 8; ++c) {
            bf16x8 a = *(const bf16x8*)(aph + c * 32);
            bf16x8 al = *(const bf16x8*)(apl + c * 32);
            acc = MFMA16(a, bh[c], acc, 0, 0, 0);
            acc = MFMA16(a, bl[c], acc, 0, 0, 0);
            acc = MFMA16(al, bh[c], acc, 0, 0, 0);
        }
        ushort4 h4, l4;
        #pragma unroll
        for (int r = 0; r < 4; ++r) {
            unsigned short h = f2bf(acc[r]);
            ((unsigned short*)&h4)[r] = h;
            ((unsigned short*)&l4)[r] = f2bf(acc[r] - bf2f(h));
        }
        int dbase = dt * 16 + qd * 4;
        if (dbase < 64) {
            *(ushort4*)(qh + (size_t)bn * 64 + dbase) = h4;
            *(ushort4*)(ql + (size_t)bn * 64 + dbase) = l4;
        } else {
            *(ushort4*)(kh + (size_t)bn * 64 + dbase - 64) = h4;
            *(ushort4*)(kl + (size_t)bn * 64 + dbase - 64) = l4;
        }
    }
}

// ---------------- kernel 2: QK pass -> E, rcs, scaled vT ------------------
// grid (32 mt, 8 b), 512 thr = 8 waves. wave (i = m-half, j = n-sixteenth).
// E[b][mt][n][64] = exp(S[n][m]-60) bf16. Epilogue: rcs=1/colsum, scale vT.
__global__ __launch_bounds__(512) void k_qk(
    const unsigned short* __restrict__ qh, const unsigned short* __restrict__ ql,
    const unsigned short* __restrict__ kh, const unsigned short* __restrict__ kl,
    unsigned short* __restrict__ E, unsigned short* __restrict__ rcsb,
    unsigned short* __restrict__ vT)
{
    __shared__ float csbuf[4][64];
    __shared__ float rcs_s[64];
    int tid = threadIdx.x;
    int w = tid >> 6, lane = tid & 63;
    int t = lane & 15, qd = lane >> 4;
    int b = blockIdx.y, mt = blockIdx.x, m0 = mt * 64;
    int i = w >> 2, j = w & 3;

    // persistent A-frags: k rows m0 + 32i + 16mi + t
    bf16x8 ah[2][2], al[2][2];
    #pragma unroll
    for (int mi = 0; mi < 2; ++mi) {
        const unsigned short* aph = kh + ((size_t)b * 2048 + m0 + 32 * i + 16 * mi + t) * 64 + qd * 8;
        const unsigned short* apl = kl + ((size_t)b * 2048 + m0 + 32 * i + 16 * mi + t) * 64 + qd * 8;
        ah[mi][0] = *(const bf16x8*)aph;
        ah[mi][1] = *(const bf16x8*)(aph + 32);
        al[mi][0] = *(const bf16x8*)apl;
        al[mi][1] = *(const bf16x8*)(apl + 32);
    }

    unsigned short* Eb = E + ((size_t)b * 32 + mt) * 2048 * 64;
    float ssum[2][4];
    #pragma unroll
    for (int mi = 0; mi < 2; ++mi)
        #pragma unroll
        for (int r = 0; r < 4; ++r) ssum[mi][r] = 0.f;

    for (int it = 0; it < 32; ++it) {
        int n = it * 64 + j * 16 + t;
        const unsigned short* qph = qh + ((size_t)b * 2048 + n) * 64 + qd * 8;
        const unsigned short* qpl = ql + ((size_t)b * 2048 + n) * 64 + qd * 8;
        bf16x8 bh0 = *(const bf16x8*)qph;
        bf16x8 bh1 = *(const bf16x8*)(qph + 32);
        bf16x8 bl0 = *(const bf16x8*)qpl;
        bf16x8 bl1 = *(const bf16x8*)(qpl + 32);
        #pragma unroll
        for (int mi = 0; mi < 2; ++mi) {
            f32x4 s = {0.f, 0.f, 0.f, 0.f};
            s = MFMA16(ah[mi][0], bh0, s, 0, 0, 0);
            s = MFMA16(ah[mi][1], bh1, s, 0, 0, 0);
            s = MFMA16(ah[mi][0], bl0, s, 0, 0, 0);
            s = MFMA16(ah[mi][1], bl1, s, 0, 0, 0);
            s = MFMA16(al[mi][0], bh0, s, 0, 0, 0);
            s = MFMA16(al[mi][1], bh1, s, 0, 0, 0);
            ushort4 e4;
            #pragma unroll
            for (int r = 0; r < 4; ++r) {
                float p = __expf(s[r] - COFF);
                ssum[mi][r] += p;
                ((unsigned short*)&e4)[r] = f2bf(p);
            }
            *(ushort4*)(Eb + (size_t)n * 64 + 32 * i + 16 * mi + qd * 4) = e4;
        }
    }

    // column-sum reduce over t, then over j-waves
    #pragma unroll
    for (int mi = 0; mi < 2; ++mi)
        #pragma unroll
        for (int r = 0; r < 4; ++r) {
            float v = ssum[mi][r];
            v += __shfl_xor(v, 1, 16);
            v += __shfl_xor(v, 2, 16);
            v += __shfl_xor(v, 4, 16);
            v += __shfl_xor(v, 8, 16);
            if (t == 0) {
                if (j == 0) csbuf[0][32 * i + 16 * mi + qd * 4 + r] = v;
                else        csbuf[j][32 * i + 16 * mi + qd * 4 + r] = v;
            }
        }
    __syncthreads();
    if (tid < 64) {
        float cstot = csbuf[0][tid] + csbuf[1][tid] + csbuf[2][tid] + csbuf[3][tid];
        float rc = 1.0f / cstot;
        rcs_s[tid] = rc;
        rcsb[(size_t)b * 2048 + m0 + tid] = f2bf(rc);
    }
    __syncthreads();
    // scale vT columns m0..m0+63 in place: v' = v * rcs
    {
        int d = tid >> 1, half = tid & 1;
        unsigned short* vp = vT + ((size_t)b * 256 + d) * 2048 + m0 + half * 32;
        #pragma unroll
        for (int e = 0; e < 4; ++e) {
            bf16x8 v8 = *(bf16x8*)(vp + e * 8);
            #pragma unroll
            for (int u = 0; u < 8; ++u) {
                float f = bf2f((unsigned short)v8[u]) * rcs_s[half * 32 + e * 8 + u];
                v8[u] = (short)f2bf(f);
            }
            *(bf16x8*)(vp + e * 8) = v8;
        }
    }
}

// ---------------- kernel 3: PV pass: out = (E·v') / rs --------------------
// grid (32 nt, 8 b), 256 thr = 4 waves; wave w: d-range [64w, 64w+64).
// Wave tile 64n x 64d; A=E, B=v' direct from global (L2). rs via rcs-col MFMA.
__global__ __launch_bounds__(256) void k_pv(
    const unsigned short* __restrict__ E, const unsigned short* __restrict__ rcsb,
    const unsigned short* __restrict__ vT, float* __restrict__ out)
{
    __shared__ float rsbuf[64];
    int tid = threadIdx.x;
    int w = tid >> 6, lane = tid & 63;
    int t = lane & 15, qd = lane >> 4;
    int b = blockIdx.y, n0 = blockIdx.x * 64;

    const unsigned short* Eb = E + (size_t)b * 32 * 2048 * 64;
    f32x4 acc[4][4];
    #pragma unroll
    for (int g = 0; g < 4; ++g)
        #pragma unroll
        for (int c = 0; c < 4; ++c) acc[g][c] = (f32x4){0.f, 0.f, 0.f, 0.f};
    f32x4 ars = {0.f, 0.f, 0.f, 0.f};
    const bf16x8 zero8 = {0, 0, 0, 0, 0, 0, 0, 0};

    #pragma unroll 1
    for (int mt = 0; mt < 32; ++mt) {
        const unsigned short* Es = Eb + (size_t)mt * (2048 * 64);
        bf16x8 AE[4][2], BV[4][2], BR[2];
        #pragma unroll
        for (int g = 0; g < 4; ++g) {
            const unsigned short* ap = Es + (size_t)(n0 + 16 * g + t) * 64 + qd * 8;
            AE[g][0] = *(const bf16x8*)ap;
            AE[g][1] = *(const bf16x8*)(ap + 32);
        }
        #pragma unroll
        for (int c = 0; c < 4; ++c) {
            const unsigned short* bp = vT + ((size_t)b * 256 + w * 64 + 16 * c + t) * 2048 + mt * 64 + qd * 8;
            BV[c][0] = *(const bf16x8*)bp;
            BV[c][1] = *(const bf16x8*)(bp + 32);
        }
        {
            const unsigned short* rp = rcsb + (size_t)b * 2048 + mt * 64 + qd * 8;
            BR[0] = (t == 0) ? *(const bf16x8*)rp : zero8;
            BR[1] = (t == 0) ? *(const bf16x8*)(rp + 32) : zero8;
        }
        #pragma unroll
        for (int g = 0; g < 4; ++g)
            #pragma unroll
            for (int c = 0; c < 4; ++c) {
                acc[g][c] = MFMA16(AE[g][0], BV[c][0], acc[g][c], 0, 0, 0);
                acc[g][c] = MFMA16(AE[g][1], BV[c][1], acc[g][c], 0, 0, 0);
            }
        ars = MFMA16(AE[w][0], BR[0], ars, 0, 0, 0);
        ars = MFMA16(AE[w][1], BR[1], ars, 0, 0, 0);
    }

    if (t == 0) {
        #pragma unroll
        for (int r = 0; r < 4; ++r) rsbuf[16 * w + qd * 4 + r] = ars[r];
    }
    __syncthreads();

    #pragma unroll
    for (int g = 0; g < 4; ++g)
        #pragma unroll
        for (int r = 0; r < 4; ++r) {
            int nl = 16 * g + qd * 4 + r;
            float sc = 1.0f / (1e-9f + rsbuf[nl]);
            size_t orow = ((size_t)b * 2048 + n0 + nl) * 256;
            #pragma unroll
            for (int c = 0; c < 4; ++c)
                out[orow + w * 64 + 16 * c + t] = acc[g][c][r] * sc;
        }
}

extern "C" void kernel_launch(void* const* d_in, const int* in_sizes, int n_in,
                              void* d_out, int out_size, void* d_ws, size_t ws_size,
                              hipStream_t stream) {
    (void)in_sizes; (void)n_in; (void)out_size; (void)ws_size;
    const float* x  = (const float*)d_in[0];
    const float* Wq = (const float*)d_in[1];
    const float* Wk = (const float*)d_in[2];
    const float* Wv = (const float*)d_in[3];
    float* out = (float*)d_out;

    char* ws = (char*)d_ws;
    size_t off = 0;
    unsigned short* Wh = (unsigned short*)(ws + off); off += (size_t)384 * 256 * 2;
    unsigned short* Wl = (unsigned short*)(ws + off); off += (size_t)384 * 256 * 2;
    unsigned short* xh = (unsigned short*)(ws + off); off += (size_t)BB * NN * CC * 2;
    unsigned short* xl = (unsigned short*)(ws + off); off += (size_t)BB * NN * CC * 2;
    unsigned short* qh = (unsigned short*)(ws + off); off += (size_t)BB * NN * DKK * 2;
    unsigned short* ql = (unsigned short*)(ws + off); off += (size_t)BB * NN * DKK * 2;
    unsigned short* kh = (unsigned short*)(ws + off); off += (size_t)BB * NN * DKK * 2;
    unsigned short* kl = (unsigned short*)(ws + off); off += (size_t)BB * NN * DKK * 2;
    unsigned short* vT = (unsigned short*)(ws + off); off += (size_t)BB * DVV * NN * 2;
    unsigned short* rcsb = (unsigned short*)(ws + off); off += (size_t)BB * NN * 2;
    unsigned short* E  = (unsigned short*)(ws + off); off += (size_t)BB * NN * NN * 2;

    hipLaunchKernelGGL(k_wt,     dim3(384),         dim3(256), 0, stream, Wq, Wk, Wv, Wh, Wl);
    hipLaunchKernelGGL(k_split,  dim3(2048),        dim3(256), 0, stream, x, xh, xl);
    hipLaunchKernelGGL(k_vproj,  dim3(1024),        dim3(256), 0, stream, xh, Wh, vT);
    hipLaunchKernelGGL(k_qkproj, dim3(1024),        dim3(256), 0, stream, xh, xl, Wh, Wl, qh, ql, kh, kl);
    hipLaunchKernelGGL(k_qk,     dim3(NN / 64, BB), dim3(512), 0, stream, qh, ql, kh, kl, E, rcsb, vT);
    hipLaunchKernelGGL(k_pv,     dim3(NN / 64, BB), dim3(256), 0, stream, E, rcsb, vT, out);
}